// Round 8
// baseline (734.543 us; speedup 1.0000x reference)
//
#include <hip/hip_runtime.h>

#define HEADS  16
#define DH     64
#define NBATCH 2
#define SEQ    2048
#define DMODEL 1024

typedef unsigned short u16;
typedef unsigned int   u32;
typedef unsigned long long u64;

typedef __attribute__((ext_vector_type(8))) short short8v;   // 8 bf16
typedef __attribute__((ext_vector_type(4))) float floatx4;

__device__ __forceinline__ u16 f2bf(float f) {
    u32 u = __float_as_uint(f);
    return (u16)((u + 0x7fffu + ((u >> 16) & 1u)) >> 16);
}
__device__ __forceinline__ float bf2f(u16 h) {
    return __uint_as_float(((u32)h) << 16);
}
__device__ __forceinline__ float fexp2(float x) {
    return __builtin_amdgcn_exp2f(x);    // single v_exp_f32 (2^x)
}
__device__ __forceinline__ u32 pk_bf16(float a, float b) {
    u32 r;
    asm("v_cvt_pk_bf16_f32 %0, %1, %2" : "=v"(r) : "v"(a), "v"(b));
    return r;
}

// XOR-swizzled LDS index (u16 units, stride 64, 16B-slot swizzle)
#define KSWZ(row, col) (((row) << 6) + ((col) ^ (((row) & 7) << 3)))

// ---------------- split x into hi/lo bf16 ----------------
__global__ void k_split(const float* __restrict__ in, u16* __restrict__ hi,
                        u16* __restrict__ lo, int n4) {
    int i = blockIdx.x * blockDim.x + threadIdx.x;
    if (i >= n4) return;
    float4 v = reinterpret_cast<const float4*>(in)[i];
    ushort4 hv, lv;
    hv.x = f2bf(v.x); hv.y = f2bf(v.y); hv.z = f2bf(v.z); hv.w = f2bf(v.w);
    lv.x = f2bf(v.x - bf2f(hv.x));
    lv.y = f2bf(v.y - bf2f(hv.y));
    lv.z = f2bf(v.z - bf2f(hv.z));
    lv.w = f2bf(v.w - bf2f(hv.w));
    reinterpret_cast<ushort4*>(hi)[i] = hv;
    reinterpret_cast<ushort4*>(lo)[i] = lv;
}

// ---------------- transpose + split: in[R][C] f32 -> hiT/loT [C][R] bf16 ----------------
__global__ void k_tsplit(const float* __restrict__ in, u16* __restrict__ hiT,
                         u16* __restrict__ loT, int R, int C, int write_lo) {
    __shared__ float tile[64][65];
    int c0 = blockIdx.x * 64, r0 = blockIdx.y * 64;
    int t = threadIdx.x;
    int lr = t >> 4;
    int lc = (t & 15) * 4;
    for (int i = 0; i < 4; i++) {
        int r = lr + i * 16;
        float4 v = *reinterpret_cast<const float4*>(&in[(size_t)(r0 + r) * C + c0 + lc]);
        tile[r][lc] = v.x; tile[r][lc + 1] = v.y; tile[r][lc + 2] = v.z; tile[r][lc + 3] = v.w;
    }
    __syncthreads();
    for (int i = 0; i < 4; i++) {
        int cc = lr + i * 16;
        float vs0 = tile[lc + 0][cc], vs1 = tile[lc + 1][cc];
        float vs2 = tile[lc + 2][cc], vs3 = tile[lc + 3][cc];
        ushort4 hv, lv;
        hv.x = f2bf(vs0); hv.y = f2bf(vs1); hv.z = f2bf(vs2); hv.w = f2bf(vs3);
        *reinterpret_cast<ushort4*>(&hiT[(size_t)(c0 + cc) * R + r0 + lc]) = hv;
        if (write_lo) {
            lv.x = f2bf(vs0 - bf2f(hv.x)); lv.y = f2bf(vs1 - bf2f(hv.y));
            lv.z = f2bf(vs2 - bf2f(hv.z)); lv.w = f2bf(vs3 - bf2f(hv.w));
            *reinterpret_cast<ushort4*>(&loT[(size_t)(c0 + cc) * R + r0 + lc]) = lv;
        }
    }
}

// ---------------- bit-pack mask (int32 0/1, True = masked) ----------------
__global__ void k_maskpack(const int* __restrict__ m, u64* __restrict__ bits) {
    int i = blockIdx.x * 256 + threadIdx.x;
    u64 b = __ballot(m[i] != 0);
    if ((threadIdx.x & 63) == 0) bits[((u32)i) >> 6] = b;
}

// ---------------- QKV GEMM (direct LDS staging; natural grid) ----------------
__global__ __launch_bounds__(256, 2) void k_qkv(
    const u16* __restrict__ xh, const u16* __restrict__ xl,
    const u16* __restrict__ whT, const u16* __restrict__ wlT,
    u16* __restrict__ qh, u16* __restrict__ ql,
    u16* __restrict__ kh, u16* __restrict__ kl,
    u16* __restrict__ vt)
{
    __shared__ __attribute__((aligned(16))) u16 sA[2][128][72];
    __shared__ __attribute__((aligned(16))) u16 sB[2][128][72];
    int n0 = blockIdx.x * 128;
    int m0 = blockIdx.y * 128;
    bool is_v = (n0 >= 2 * DMODEL);
    int tid = threadIdx.x;
    int wave = tid >> 6, lane = tid & 63;
    int wm = (wave >> 1) * 64, wn = (wave & 1) * 64;
    int lrow = lane & 15, lgrp = lane >> 4;

    floatx4 acc[4][4];
    for (int i = 0; i < 4; i++) for (int j = 0; j < 4; j++) acc[i][j] = (floatx4){0.f, 0.f, 0.f, 0.f};

    int sr = tid >> 1;
    int sc = (tid & 1) * 32;

    for (int k0 = 0; k0 < DMODEL; k0 += 64) {
        const u16* pxh = xh + (size_t)(m0 + sr) * DMODEL + k0 + sc;
        const u16* pwh = whT + (size_t)(n0 + sr) * DMODEL + k0 + sc;
        for (int i = 0; i < 4; i++) {
            *reinterpret_cast<int4*>(&sA[0][sr][sc + i * 8]) = *reinterpret_cast<const int4*>(pxh + i * 8);
            *reinterpret_cast<int4*>(&sB[0][sr][sc + i * 8]) = *reinterpret_cast<const int4*>(pwh + i * 8);
        }
        if (!is_v) {
            const u16* pxl = xl + (size_t)(m0 + sr) * DMODEL + k0 + sc;
            const u16* pwl = wlT + (size_t)(n0 + sr) * DMODEL + k0 + sc;
            for (int i = 0; i < 4; i++) {
                *reinterpret_cast<int4*>(&sA[1][sr][sc + i * 8]) = *reinterpret_cast<const int4*>(pxl + i * 8);
                *reinterpret_cast<int4*>(&sB[1][sr][sc + i * 8]) = *reinterpret_cast<const int4*>(pwl + i * 8);
            }
        }
        __syncthreads();
        for (int ks = 0; ks < 2; ks++) {
            short8v ah[4], bh_[4], al[4], bl_[4];
            for (int i = 0; i < 4; i++) {
                ah[i]  = *reinterpret_cast<const short8v*>(&sA[0][wm + i * 16 + lrow][ks * 32 + lgrp * 8]);
                bh_[i] = *reinterpret_cast<const short8v*>(&sB[0][wn + i * 16 + lrow][ks * 32 + lgrp * 8]);
            }
            if (!is_v) {
                for (int i = 0; i < 4; i++) {
                    al[i]  = *reinterpret_cast<const short8v*>(&sA[1][wm + i * 16 + lrow][ks * 32 + lgrp * 8]);
                    bl_[i] = *reinterpret_cast<const short8v*>(&sB[1][wn + i * 16 + lrow][ks * 32 + lgrp * 8]);
                }
            }
            for (int i = 0; i < 4; i++)
                for (int j = 0; j < 4; j++) {
                    acc[i][j] = __builtin_amdgcn_mfma_f32_16x16x32_bf16(ah[i], bh_[j], acc[i][j], 0, 0, 0);
                    if (!is_v) {
                        acc[i][j] = __builtin_amdgcn_mfma_f32_16x16x32_bf16(ah[i], bl_[j], acc[i][j], 0, 0, 0);
                        acc[i][j] = __builtin_amdgcn_mfma_f32_16x16x32_bf16(al[i], bh_[j], acc[i][j], 0, 0, 0);
                    }
                }
        }
        __syncthreads();
    }
    // epilogue: scatter into q/k (hi/lo, score scale folded into q) and transposed V
    for (int j = 0; j < 4; j++) {
        int c = n0 + wn + j * 16 + lrow;
        int sel = c >> 10;
        int hcol = c & 1023;
        int hh = hcol >> 6, d = hcol & 63;
        for (int i = 0; i < 4; i++) {
            int mbase = m0 + wm + i * 16 + lgrp * 4;
            int bb = mbase >> 11;
            int nn = mbase & 2047;
            int bh = bb * HEADS + hh;
            if (sel == 2) {
                ushort4 pv;
                pv.x = f2bf(acc[i][j][0]); pv.y = f2bf(acc[i][j][1]);
                pv.z = f2bf(acc[i][j][2]); pv.w = f2bf(acc[i][j][3]);
                *reinterpret_cast<ushort4*>(&vt[((size_t)bh * DH + d) * SEQ + nn]) = pv;
            } else {
                u16* oh = (sel == 0) ? qh : kh;
                u16* ol = (sel == 0) ? ql : kl;
                // fold sqrt(dh)*log2(e) = 8*1.44269504 into q (exp2-domain scores)
                float sc8 = (sel == 0) ? 11.5415603f : 1.0f;
                for (int r = 0; r < 4; r++) {
                    float v = acc[i][j][r] * sc8;
                    u16 hv = f2bf(v);
                    u16 lv = f2bf(v - bf2f(hv));
                    size_t addr = ((size_t)bh * SEQ + nn + r) * DH + d;
                    oh[addr] = hv; ol[addr] = lv;
                }
            }
        }
    }
}

// ---------------- attention: swizzled LDS staging, natural grid ----------------
__global__ __launch_bounds__(256, 3) void k_attn(
    const u16* __restrict__ qh, const u16* __restrict__ ql,
    const u16* __restrict__ kh, const u16* __restrict__ kl,
    const u16* __restrict__ vt, const u32* __restrict__ mb,
    float* __restrict__ attn, u16* __restrict__ ctx)
{
    __shared__ __attribute__((aligned(16))) u16 sKh[2][64 * 64];
    __shared__ __attribute__((aligned(16))) u16 sKl[2][64 * 64];
    __shared__ __attribute__((aligned(16))) u16 sP[2][64 * 64];
    __shared__ u32 sMask[2][64][2];
    __shared__ float sML[2][4][64];

    const float NEGBIG = -3.0e38f;

    // natural mapping: consecutive blocks = consecutive q-tiles of one head
    // (temporal L2 locality for K/V — measured better than XCD swizzling, R7)
    int bh = blockIdx.y;
    int q0 = blockIdx.x * 64;
    int b = bh >> 4;
    int tid = threadIdx.x, wave = tid >> 6, lane = tid & 63;
    int lrow = lane & 15, lgrp = lane >> 4;
    int mbit = (wave & 1) * 16 + lgrp * 4;   // bit base within u32 mask word
    int mwsel = wave >> 1;                   // which u32 of the 64-bit row chunk

    // K staging geometry: lane loads rows (tid>>3) and (tid>>3)+32, 16B slot (tid&7)
    int krow = tid >> 3;
    int kcol = (tid & 7) * 8;
    int ksz1 = KSWZ(krow, kcol);
    int ksz2 = KSWZ(krow + 32, kcol);

    // Q fragments (B-operand of K·Q^T), hi/lo, hoisted (64 VGPR)
    short8v qfh[4][2], qfl[4][2];
    for (int nt = 0; nt < 4; nt++) {
        int qr = q0 + nt * 16 + lrow;
        const u16* pq = qh + ((size_t)bh * SEQ + qr) * DH + lgrp * 8;
        const u16* pl = ql + ((size_t)bh * SEQ + qr) * DH + lgrp * 8;
        for (int ks = 0; ks < 2; ks++) {
            qfh[nt][ks] = *reinterpret_cast<const short8v*>(pq + ks * 32);
            qfl[nt][ks] = *reinterpret_cast<const short8v*>(pl + ks * 32);
        }
    }

    int4 ra0, ra1, rb0, rb1;   // staged K regs (load-early / write-late)
    u32 mv = 0;

#define K_LOAD(KT) do { \
        const u16* ph_ = kh + ((size_t)bh * SEQ + (KT) * 64 + krow) * DH + kcol; \
        const u16* pl_ = kl + ((size_t)bh * SEQ + (KT) * 64 + krow) * DH + kcol; \
        ra0 = *reinterpret_cast<const int4*>(ph_); \
        ra1 = *reinterpret_cast<const int4*>(ph_ + 32 * DH); \
        rb0 = *reinterpret_cast<const int4*>(pl_); \
        rb1 = *reinterpret_cast<const int4*>(pl_ + 32 * DH); \
        if (tid < 128) mv = mb[((size_t)(b * SEQ + q0 + (tid >> 1))) * 64 + (KT) * 2 + (tid & 1)]; \
    } while (0)

#define K_WRITE(B_) do { \
        *reinterpret_cast<int4*>(&sKh[B_][ksz1]) = ra0; \
        *reinterpret_cast<int4*>(&sKh[B_][ksz2]) = ra1; \
        *reinterpret_cast<int4*>(&sKl[B_][ksz1]) = rb0; \
        *reinterpret_cast<int4*>(&sKl[B_][ksz2]) = rb1; \
        if (tid < 128) sMask[B_][tid >> 1][tid & 1] = mv; \
    } while (0)

#define COMPUTE_ST(CUR) do { \
        for (int nt_ = 0; nt_ < 4; nt_++) sacc[nt_] = (floatx4){0.f, 0.f, 0.f, 0.f}; \
        __builtin_amdgcn_s_setprio(1); \
        for (int ks_ = 0; ks_ < 2; ks_++) { \
            int a_ = KSWZ(wave * 16 + lrow, ks_ * 32 + lgrp * 8); \
            short8v kfh_ = *reinterpret_cast<const short8v*>(&sKh[CUR][a_]); \
            short8v kfl_ = *reinterpret_cast<const short8v*>(&sKl[CUR][a_]); \
            for (int nt_ = 0; nt_ < 4; nt_++) { \
                sacc[nt_] = __builtin_amdgcn_mfma_f32_16x16x32_bf16(kfh_, qfh[nt_][ks_], sacc[nt_], 0, 0, 0); \
                sacc[nt_] = __builtin_amdgcn_mfma_f32_16x16x32_bf16(kfh_, qfl[nt_][ks_], sacc[nt_], 0, 0, 0); \
                sacc[nt_] = __builtin_amdgcn_mfma_f32_16x16x32_bf16(kfl_, qfh[nt_][ks_], sacc[nt_], 0, 0, 0); \
            } \
        } \
        __builtin_amdgcn_s_setprio(0); \
    } while (0)

    // per-LANE online (m,l): no cross-lane ops in the hot loop
    float m_run[4], l_run[4];
    for (int nt = 0; nt < 4; nt++) { m_run[nt] = -1.0e38f; l_run[nt] = 0.f; }

    // ---- pass A: 1 barrier/iter, dbuf K ----
    K_LOAD(0);
    K_WRITE(0);
    __syncthreads();
    for (int kt = 0; kt < 32; kt++) {
        int cur = kt & 1;
        if (kt < 31) K_LOAD(kt + 1);
        floatx4 sacc[4];
        COMPUTE_ST(cur);
        for (int nt = 0; nt < 4; nt++) {
            u32 nw = ~sMask[cur][nt * 16 + lrow][mwsel];
            float sm0 = ((nw >> (mbit + 0)) & 1u) ? sacc[nt][0] : NEGBIG;
            float sm1 = ((nw >> (mbit + 1)) & 1u) ? sacc[nt][1] : NEGBIG;
            float sm2 = ((nw >> (mbit + 2)) & 1u) ? sacc[nt][2] : NEGBIG;
            float sm3 = ((nw >> (mbit + 3)) & 1u) ? sacc[nt][3] : NEGBIG;
            float tmax = fmaxf(fmaxf(sm0, sm1), fmaxf(sm2, sm3));
            float mn = fmaxf(m_run[nt], tmax);
            float ssum = fexp2(sm0 - mn) + fexp2(sm1 - mn) + fexp2(sm2 - mn) + fexp2(sm3 - mn);
            l_run[nt] = l_run[nt] * fexp2(m_run[nt] - mn) + ssum;
            m_run[nt] = mn;
        }
        if (kt < 31) K_WRITE(cur ^ 1);
        __syncthreads();
    }

    // lane merge (once): lgrp 0..3 hold partial (m,l) for q-row (lane&15)
    for (int nt = 0; nt < 4; nt++) {
        float m = m_run[nt], l = l_run[nt];
        for (int off = 16; off <= 32; off <<= 1) {
            float mo = __shfl_xor(m, off);
            float lo2 = __shfl_xor(l, off);
            float mn = fmaxf(m, mo);
            l = l * fexp2(m - mn) + lo2 * fexp2(mo - mn);
            m = mn;
        }
        m_run[nt] = m; l_run[nt] = l;
    }
    // cross-wave merge -> Cn = m_fin + log2(l_total); l_total >= 1 always
    if (lane < 16) {
        for (int nt = 0; nt < 4; nt++) {
            sML[0][wave][nt * 16 + lane] = m_run[nt];
            sML[1][wave][nt * 16 + lane] = l_run[nt];
        }
    }
    __syncthreads();
    float Cn[4];
    for (int nt = 0; nt < 4; nt++) {
        int qr = nt * 16 + lrow;
        float m4 = sML[0][0][qr];
        for (int w = 1; w < 4; w++) m4 = fmaxf(m4, sML[0][w][qr]);
        float ls = 0.f;
        for (int w = 0; w < 4; w++) ls += sML[1][w][qr] * fexp2(sML[0][w][qr] - m4);
        Cn[nt] = m4 + __log2f(ls);    // p = exp2(sm - Cn)
    }

    floatx4 cacc[4];
    for (int j = 0; j < 4; j++) cacc[j] = (floatx4){0.f, 0.f, 0.f, 0.f};

    // ---- pass B: recompute S, write attn, PV; 1 barrier/iter (dbuf K + dbuf sP) ----
    K_LOAD(0);
    K_WRITE(0);
    __syncthreads();
    for (int kt = 0; kt < 32; kt++) {
        int cur = kt & 1;
        // V fragments for this tile (L2-resident); latency hides under MFMA
        int4 vreg[4][2];
        for (int j = 0; j < 4; j++)
            for (int ks = 0; ks < 2; ks++)
                vreg[j][ks] = *reinterpret_cast<const int4*>(
                    vt + ((size_t)bh * DH + j * 16 + lrow) * SEQ + kt * 64 + ks * 32 + lgrp * 8);
        if (kt < 31) K_LOAD(kt + 1);
        floatx4 sacc[4];
        COMPUTE_ST(cur);
        for (int nt = 0; nt < 4; nt++) {
            u32 nw = ~sMask[cur][nt * 16 + lrow][mwsel];
            int qr = q0 + nt * 16 + lrow;
            float4 pf4;
            float* pp = &pf4.x;
            for (int r = 0; r < 4; r++) {
                // masked -> sm = -3e38 -> exp2 == 0 exactly; unmasked -> sm - Cn <= 0
                float sm = ((nw >> (mbit + r)) & 1u) ? sacc[nt][r] : NEGBIG;
                pp[r] = fexp2(sm - Cn[nt]);
            }
            int kc = kt * 64 + wave * 16 + lgrp * 4;
            *reinterpret_cast<float4*>(&attn[((size_t)bh * SEQ + qr) * SEQ + kc]) = pf4;
            uint2 pw;
            pw.x = pk_bf16(pp[0], pp[1]);
            pw.y = pk_bf16(pp[2], pp[3]);
            *reinterpret_cast<uint2*>(&sP[cur][KSWZ(nt * 16 + lrow, wave * 16 + lgrp * 4)]) = pw;
        }
        if (kt < 31) K_WRITE(cur ^ 1);
        __syncthreads();     // sP[cur] published + sK[cur^1] staged
        __builtin_amdgcn_s_setprio(1);
        for (int ks = 0; ks < 2; ks++) {
            short8v pfrag = *reinterpret_cast<const short8v*>(&sP[cur][KSWZ(wave * 16 + lrow, ks * 32 + lgrp * 8)]);
            for (int j = 0; j < 4; j++) {
                short8v vfrag = *reinterpret_cast<short8v*>(&vreg[j][ks]);
                cacc[j] = __builtin_amdgcn_mfma_f32_16x16x32_bf16(pfrag, vfrag, cacc[j], 0, 0, 0);
            }
        }
        __builtin_amdgcn_s_setprio(0);
    }
    // write context (bf16) into [b, n, h*dh]
    int hh = bh & 15;
    for (int j = 0; j < 4; j++) {
        int d = j * 16 + lrow;
        for (int r = 0; r < 4; r++) {
            int nn = q0 + wave * 16 + lgrp * 4 + r;
            ctx[((size_t)b * SEQ + nn) * DMODEL + hh * 64 + d] = f2bf(cacc[j][r]);
        }
    }
#undef K_LOAD
#undef K_WRITE
#undef COMPUTE_ST
}

// ---------------- out = ctx @ Wfc (natural grid) ----------------
__global__ __launch_bounds__(256, 2) void k_out(
    const u16* __restrict__ ctx, const u16* __restrict__ wfcT, float* __restrict__ out)
{
    __shared__ __attribute__((aligned(16))) u16 sA[128][72];
    __shared__ __attribute__((aligned(16))) u16 sB[128][72];
    int n0 = blockIdx.x * 128;
    int m0 = blockIdx.y * 128;
    int tid = threadIdx.x;
    int wave = tid >> 6, lane = tid & 63;
    int wm = (wave >> 1) * 64, wn = (wave & 1) * 64;
    int lrow = lane & 15, lgrp = lane >> 4;

    floatx4 acc[4][4];
    for (int i = 0; i < 4; i++) for (int j = 0; j < 4; j++) acc[i][j] = (floatx4){0.f, 0.f, 0.f, 0.f};

    int sr = tid >> 1;
    int sc = (tid & 1) * 32;

    for (int k0 = 0; k0 < DMODEL; k0 += 64) {
        const u16* pa = ctx + (size_t)(m0 + sr) * DMODEL + k0 + sc;
        const u16* pb = wfcT + (size_t)(n0 + sr) * DMODEL + k0 + sc;
        for (int i = 0; i < 4; i++) {
            *reinterpret_cast<int4*>(&sA[sr][sc + i * 8]) = *reinterpret_cast<const int4*>(pa + i * 8);
            *reinterpret_cast<int4*>(&sB[sr][sc + i * 8]) = *reinterpret_cast<const int4*>(pb + i * 8);
        }
        __syncthreads();
        for (int ks = 0; ks < 2; ks++) {
            short8v af[4], bf[4];
            for (int i = 0; i < 4; i++) {
                af[i] = *reinterpret_cast<const short8v*>(&sA[wm + i * 16 + lrow][ks * 32 + lgrp * 8]);
                bf[i] = *reinterpret_cast<const short8v*>(&sB[wn + i * 16 + lrow][ks * 32 + lgrp * 8]);
            }
            for (int i = 0; i < 4; i++)
                for (int j = 0; j < 4; j++)
                    acc[i][j] = __builtin_amdgcn_mfma_f32_16x16x32_bf16(af[i], bf[j], acc[i][j], 0, 0, 0);
        }
        __syncthreads();
    }
    for (int i = 0; i < 4; i++)
        for (int j = 0; j < 4; j++)
            for (int r = 0; r < 4; r++) {
                int m = m0 + wm + i * 16 + lgrp * 4 + r;
                int c = n0 + wn + j * 16 + lrow;
                out[(size_t)m * DMODEL + c] = acc[i][j][r];
            }
}

extern "C" void kernel_launch(void* const* d_in, const int* in_sizes, int n_in,
                              void* d_out, int out_size, void* d_ws, size_t ws_size,
                              hipStream_t stream) {
    const float* x    = (const float*)d_in[0];
    const int*   mask = (const int*)d_in[1];
    const float* wqkv = (const float*)d_in[2];
    const float* wfc  = (const float*)d_in[3];

    float* out  = (float*)d_out;
    float* attn = out + (size_t)NBATCH * SEQ * DMODEL;

    u16* xh   = (u16*)d_ws;                 // 4096*1024
    u16* xl   = xh + 4194304;
    u16* whT  = xl + 4194304;               // 3072*1024
    u16* wlT  = whT + 3145728;
    u16* wfcT = wlT + 3145728;              // 1024*1024
    u16* qh   = wfcT + 1048576;             // 32*2048*64 each
    u16* ql   = qh + 4194304;
    u16* kh   = ql + 4194304;
    u16* kl   = kh + 4194304;
    u16* vt   = kl + 4194304;
    u32* mbits = (u32*)(vt + 4194304);      // 2*2048*64 words
    u16* ctx  = xh;                         // overlay: x splits dead after k_qkv

    k_split<<<4096, 256, 0, stream>>>(x, xh, xl, 4194304 / 4);
    k_tsplit<<<dim3(48, 16), 256, 0, stream>>>(wqkv, whT, wlT, 1024, 3072, 1);
    k_tsplit<<<dim3(16, 16), 256, 0, stream>>>(wfc, wfcT, (u16*)nullptr, 1024, 1024, 0);
    k_maskpack<<<32768, 256, 0, stream>>>(mask, (u64*)mbits);
    k_qkv<<<dim3(24, 32), 256, 0, stream>>>(xh, xl, whT, wlT, qh, ql, kh, kl, vt);
    k_attn<<<dim3(32, 32), 256, 0, stream>>>(qh, ql, kh, kl, vt, mbits, attn, ctx);
    k_out<<<dim3(8, 32), 256, 0, stream>>>(ctx, wfcT, out);
}

// Round 9
// 478.757 us; speedup vs baseline: 1.5343x; 1.5343x over previous
//
#include <hip/hip_runtime.h>

#define HEADS  16
#define DH     64
#define NBATCH 2
#define SEQ    2048
#define DMODEL 1024

typedef unsigned short u16;
typedef unsigned int   u32;
typedef unsigned long long u64;

typedef __attribute__((ext_vector_type(8))) short short8v;   // 8 bf16
typedef __attribute__((ext_vector_type(4))) float floatx4;

__device__ __forceinline__ u16 f2bf(float f) {
    u32 u = __float_as_uint(f);
    return (u16)((u + 0x7fffu + ((u >> 16) & 1u)) >> 16);
}
__device__ __forceinline__ float bf2f(u16 h) {
    return __uint_as_float(((u32)h) << 16);
}
__device__ __forceinline__ float fexp2(float x) {
    return __builtin_amdgcn_exp2f(x);    // single v_exp_f32 (2^x)
}
__device__ __forceinline__ u32 pk_bf16(float a, float b) {
    u32 r;
    asm("v_cvt_pk_bf16_f32 %0, %1, %2" : "=v"(r) : "v"(a), "v"(b));
    return r;
}

// XOR-swizzled LDS index (u16 units, stride 64, 16B-slot swizzle)
#define KSWZ(row, col) (((row) << 6) + ((col) ^ (((row) & 7) << 3)))

// ---------------- split x into hi/lo bf16 ----------------
__global__ void k_split(const float* __restrict__ in, u16* __restrict__ hi,
                        u16* __restrict__ lo, int n4) {
    int i = blockIdx.x * blockDim.x + threadIdx.x;
    if (i >= n4) return;
    float4 v = reinterpret_cast<const float4*>(in)[i];
    ushort4 hv, lv;
    hv.x = f2bf(v.x); hv.y = f2bf(v.y); hv.z = f2bf(v.z); hv.w = f2bf(v.w);
    lv.x = f2bf(v.x - bf2f(hv.x));
    lv.y = f2bf(v.y - bf2f(hv.y));
    lv.z = f2bf(v.z - bf2f(hv.z));
    lv.w = f2bf(v.w - bf2f(hv.w));
    reinterpret_cast<ushort4*>(hi)[i] = hv;
    reinterpret_cast<ushort4*>(lo)[i] = lv;
}

// ---------------- transpose + split: in[R][C] f32 -> hiT/loT [C][R] bf16 ----------------
__global__ void k_tsplit(const float* __restrict__ in, u16* __restrict__ hiT,
                         u16* __restrict__ loT, int R, int C, int write_lo) {
    __shared__ float tile[64][65];
    int c0 = blockIdx.x * 64, r0 = blockIdx.y * 64;
    int t = threadIdx.x;
    int lr = t >> 4;
    int lc = (t & 15) * 4;
    for (int i = 0; i < 4; i++) {
        int r = lr + i * 16;
        float4 v = *reinterpret_cast<const float4*>(&in[(size_t)(r0 + r) * C + c0 + lc]);
        tile[r][lc] = v.x; tile[r][lc + 1] = v.y; tile[r][lc + 2] = v.z; tile[r][lc + 3] = v.w;
    }
    __syncthreads();
    for (int i = 0; i < 4; i++) {
        int cc = lr + i * 16;
        float vs0 = tile[lc + 0][cc], vs1 = tile[lc + 1][cc];
        float vs2 = tile[lc + 2][cc], vs3 = tile[lc + 3][cc];
        ushort4 hv, lv;
        hv.x = f2bf(vs0); hv.y = f2bf(vs1); hv.z = f2bf(vs2); hv.w = f2bf(vs3);
        *reinterpret_cast<ushort4*>(&hiT[(size_t)(c0 + cc) * R + r0 + lc]) = hv;
        if (write_lo) {
            lv.x = f2bf(vs0 - bf2f(hv.x)); lv.y = f2bf(vs1 - bf2f(hv.y));
            lv.z = f2bf(vs2 - bf2f(hv.z)); lv.w = f2bf(vs3 - bf2f(hv.w));
            *reinterpret_cast<ushort4*>(&loT[(size_t)(c0 + cc) * R + r0 + lc]) = lv;
        }
    }
}

// ---------------- bit-pack mask (int32 0/1, True = masked) ----------------
__global__ void k_maskpack(const int* __restrict__ m, u64* __restrict__ bits) {
    int i = blockIdx.x * 256 + threadIdx.x;
    u64 b = __ballot(m[i] != 0);
    if ((threadIdx.x & 63) == 0) bits[((u32)i) >> 6] = b;
}

// ---------------- QKV GEMM (direct LDS staging; natural grid) ----------------
__global__ __launch_bounds__(256, 2) void k_qkv(
    const u16* __restrict__ xh, const u16* __restrict__ xl,
    const u16* __restrict__ whT, const u16* __restrict__ wlT,
    u16* __restrict__ qh, u16* __restrict__ ql,
    u16* __restrict__ kh, u16* __restrict__ kl,
    u16* __restrict__ vt)
{
    __shared__ __attribute__((aligned(16))) u16 sA[2][128][72];
    __shared__ __attribute__((aligned(16))) u16 sB[2][128][72];
    int n0 = blockIdx.x * 128;
    int m0 = blockIdx.y * 128;
    bool is_v = (n0 >= 2 * DMODEL);
    int tid = threadIdx.x;
    int wave = tid >> 6, lane = tid & 63;
    int wm = (wave >> 1) * 64, wn = (wave & 1) * 64;
    int lrow = lane & 15, lgrp = lane >> 4;

    floatx4 acc[4][4];
    for (int i = 0; i < 4; i++) for (int j = 0; j < 4; j++) acc[i][j] = (floatx4){0.f, 0.f, 0.f, 0.f};

    int sr = tid >> 1;
    int sc = (tid & 1) * 32;

    for (int k0 = 0; k0 < DMODEL; k0 += 64) {
        const u16* pxh = xh + (size_t)(m0 + sr) * DMODEL + k0 + sc;
        const u16* pwh = whT + (size_t)(n0 + sr) * DMODEL + k0 + sc;
        for (int i = 0; i < 4; i++) {
            *reinterpret_cast<int4*>(&sA[0][sr][sc + i * 8]) = *reinterpret_cast<const int4*>(pxh + i * 8);
            *reinterpret_cast<int4*>(&sB[0][sr][sc + i * 8]) = *reinterpret_cast<const int4*>(pwh + i * 8);
        }
        if (!is_v) {
            const u16* pxl = xl + (size_t)(m0 + sr) * DMODEL + k0 + sc;
            const u16* pwl = wlT + (size_t)(n0 + sr) * DMODEL + k0 + sc;
            for (int i = 0; i < 4; i++) {
                *reinterpret_cast<int4*>(&sA[1][sr][sc + i * 8]) = *reinterpret_cast<const int4*>(pxl + i * 8);
                *reinterpret_cast<int4*>(&sB[1][sr][sc + i * 8]) = *reinterpret_cast<const int4*>(pwl + i * 8);
            }
        }
        __syncthreads();
        for (int ks = 0; ks < 2; ks++) {
            short8v ah[4], bh_[4], al[4], bl_[4];
            for (int i = 0; i < 4; i++) {
                ah[i]  = *reinterpret_cast<const short8v*>(&sA[0][wm + i * 16 + lrow][ks * 32 + lgrp * 8]);
                bh_[i] = *reinterpret_cast<const short8v*>(&sB[0][wn + i * 16 + lrow][ks * 32 + lgrp * 8]);
            }
            if (!is_v) {
                for (int i = 0; i < 4; i++) {
                    al[i]  = *reinterpret_cast<const short8v*>(&sA[1][wm + i * 16 + lrow][ks * 32 + lgrp * 8]);
                    bl_[i] = *reinterpret_cast<const short8v*>(&sB[1][wn + i * 16 + lrow][ks * 32 + lgrp * 8]);
                }
            }
            for (int i = 0; i < 4; i++)
                for (int j = 0; j < 4; j++) {
                    acc[i][j] = __builtin_amdgcn_mfma_f32_16x16x32_bf16(ah[i], bh_[j], acc[i][j], 0, 0, 0);
                    if (!is_v) {
                        acc[i][j] = __builtin_amdgcn_mfma_f32_16x16x32_bf16(ah[i], bl_[j], acc[i][j], 0, 0, 0);
                        acc[i][j] = __builtin_amdgcn_mfma_f32_16x16x32_bf16(al[i], bh_[j], acc[i][j], 0, 0, 0);
                    }
                }
        }
        __syncthreads();
    }
    // epilogue: scatter into q/k (hi/lo, score scale folded into q) and transposed V
    for (int j = 0; j < 4; j++) {
        int c = n0 + wn + j * 16 + lrow;
        int sel = c >> 10;
        int hcol = c & 1023;
        int hh = hcol >> 6, d = hcol & 63;
        for (int i = 0; i < 4; i++) {
            int mbase = m0 + wm + i * 16 + lgrp * 4;
            int bb = mbase >> 11;
            int nn = mbase & 2047;
            int bh = bb * HEADS + hh;
            if (sel == 2) {
                ushort4 pv;
                pv.x = f2bf(acc[i][j][0]); pv.y = f2bf(acc[i][j][1]);
                pv.z = f2bf(acc[i][j][2]); pv.w = f2bf(acc[i][j][3]);
                *reinterpret_cast<ushort4*>(&vt[((size_t)bh * DH + d) * SEQ + nn]) = pv;
            } else {
                u16* oh = (sel == 0) ? qh : kh;
                u16* ol = (sel == 0) ? ql : kl;
                // fold sqrt(dh)*log2(e) = 8*1.44269504 into q (exp2-domain scores)
                float sc8 = (sel == 0) ? 11.5415603f : 1.0f;
                for (int r = 0; r < 4; r++) {
                    float v = acc[i][j][r] * sc8;
                    u16 hv = f2bf(v);
                    u16 lv = f2bf(v - bf2f(hv));
                    size_t addr = ((size_t)bh * SEQ + nn + r) * DH + d;
                    oh[addr] = hv; ol[addr] = lv;
                }
            }
        }
    }
}

// ---------------- attention: 2 blocks/CU (L2-fit), prefetch-2 K staging ----------------
__global__ __launch_bounds__(256, 2) void k_attn(
    const u16* __restrict__ qh, const u16* __restrict__ ql,
    const u16* __restrict__ kh, const u16* __restrict__ kl,
    const u16* __restrict__ vt, const u32* __restrict__ mb,
    float* __restrict__ attn, u16* __restrict__ ctx)
{
    __shared__ __attribute__((aligned(16))) u16 sKh[2][64 * 64];
    __shared__ __attribute__((aligned(16))) u16 sKl[2][64 * 64];
    __shared__ __attribute__((aligned(16))) u16 sP[2][64 * 64];
    __shared__ u32 sMask[2][64][2];
    __shared__ float sML[2][4][64];
    extern __shared__ u16 lds_pad[];   // 4KB dummy: forces <=2 blocks/CU (L2-fit, R8 lesson)

    const float NEGBIG = -3.0e38f;

    // natural mapping: consecutive blocks = consecutive q-tiles of one head
    int bh = blockIdx.y;
    int q0 = blockIdx.x * 64;
    int b = bh >> 4;
    int tid = threadIdx.x, wave = tid >> 6, lane = tid & 63;
    int lrow = lane & 15, lgrp = lane >> 4;
    int mbit = (wave & 1) * 16 + lgrp * 4;
    int mwsel = wave >> 1;

    // K staging geometry: lane covers rows (tid>>3), (tid>>3)+32 at 16B slot (tid&7)
    int krow = tid >> 3;
    int kcol = (tid & 7) * 8;
    int ksz1 = KSWZ(krow, kcol);
    int ksz2 = KSWZ(krow + 32, kcol);

    // Q fragments (B-operand of K·Q^T), hi/lo, hoisted
    short8v qfh[4][2], qfl[4][2];
    for (int nt = 0; nt < 4; nt++) {
        int qr = q0 + nt * 16 + lrow;
        const u16* pq = qh + ((size_t)bh * SEQ + qr) * DH + lgrp * 8;
        const u16* pl = ql + ((size_t)bh * SEQ + qr) * DH + lgrp * 8;
        for (int ks = 0; ks < 2; ks++) {
            qfh[nt][ks] = *reinterpret_cast<const short8v*>(pq + ks * 32);
            qfl[nt][ks] = *reinterpret_cast<const short8v*>(pl + ks * 32);
        }
    }

    // two staged register sets (prefetch distance 2)
    int4 a0, a1, a2, a3; u32 mvA;
    int4 b0, b1, b2, b3; u32 mvB;

#define K_LOAD(KT, R0, R1, R2, R3, MV) do { \
        const u16* ph_ = kh + ((size_t)bh * SEQ + (KT) * 64 + krow) * DH + kcol; \
        const u16* pl_ = kl + ((size_t)bh * SEQ + (KT) * 64 + krow) * DH + kcol; \
        R0 = *reinterpret_cast<const int4*>(ph_); \
        R1 = *reinterpret_cast<const int4*>(ph_ + 32 * DH); \
        R2 = *reinterpret_cast<const int4*>(pl_); \
        R3 = *reinterpret_cast<const int4*>(pl_ + 32 * DH); \
        if (tid < 128) MV = mb[((size_t)(b * SEQ + q0 + (tid >> 1))) * 64 + (KT) * 2 + (tid & 1)]; \
    } while (0)

#define K_WRITE(BUF, R0, R1, R2, R3, MV) do { \
        *reinterpret_cast<int4*>(&sKh[BUF][ksz1]) = R0; \
        *reinterpret_cast<int4*>(&sKh[BUF][ksz2]) = R1; \
        *reinterpret_cast<int4*>(&sKl[BUF][ksz1]) = R2; \
        *reinterpret_cast<int4*>(&sKl[BUF][ksz2]) = R3; \
        if (tid < 128) sMask[BUF][tid >> 1][tid & 1] = MV; \
    } while (0)

#define COMPUTE_ST(CUR) do { \
        for (int nt_ = 0; nt_ < 4; nt_++) sacc[nt_] = (floatx4){0.f, 0.f, 0.f, 0.f}; \
        __builtin_amdgcn_s_setprio(1); \
        for (int ks_ = 0; ks_ < 2; ks_++) { \
            int ad_ = KSWZ(wave * 16 + lrow, ks_ * 32 + lgrp * 8); \
            short8v kfh_ = *reinterpret_cast<const short8v*>(&sKh[CUR][ad_]); \
            short8v kfl_ = *reinterpret_cast<const short8v*>(&sKl[CUR][ad_]); \
            for (int nt_ = 0; nt_ < 4; nt_++) { \
                sacc[nt_] = __builtin_amdgcn_mfma_f32_16x16x32_bf16(kfh_, qfh[nt_][ks_], sacc[nt_], 0, 0, 0); \
                sacc[nt_] = __builtin_amdgcn_mfma_f32_16x16x32_bf16(kfh_, qfl[nt_][ks_], sacc[nt_], 0, 0, 0); \
                sacc[nt_] = __builtin_amdgcn_mfma_f32_16x16x32_bf16(kfl_, qfh[nt_][ks_], sacc[nt_], 0, 0, 0); \
            } \
        } \
        __builtin_amdgcn_s_setprio(0); \
    } while (0)

#define SOFTMAX_A(CUR) do { \
        for (int nt = 0; nt < 4; nt++) { \
            u32 nw = ~sMask[CUR][nt * 16 + lrow][mwsel]; \
            float sm0 = ((nw >> (mbit + 0)) & 1u) ? sacc[nt][0] : NEGBIG; \
            float sm1 = ((nw >> (mbit + 1)) & 1u) ? sacc[nt][1] : NEGBIG; \
            float sm2 = ((nw >> (mbit + 2)) & 1u) ? sacc[nt][2] : NEGBIG; \
            float sm3 = ((nw >> (mbit + 3)) & 1u) ? sacc[nt][3] : NEGBIG; \
            float tmax = fmaxf(fmaxf(sm0, sm1), fmaxf(sm2, sm3)); \
            float mn = fmaxf(m_run[nt], tmax); \
            float ssum = fexp2(sm0 - mn) + fexp2(sm1 - mn) + fexp2(sm2 - mn) + fexp2(sm3 - mn); \
            l_run[nt] = l_run[nt] * fexp2(m_run[nt] - mn) + ssum; \
            m_run[nt] = mn; \
        } \
    } while (0)

    float m_run[4], l_run[4];
    for (int nt = 0; nt < 4; nt++) { m_run[nt] = -1.0e38f; l_run[nt] = 0.f; }

    // ---- pass A: prefetch-2, 1 barrier/iter ----
    K_LOAD(0, b0, b1, b2, b3, mvB);
    K_WRITE(0, b0, b1, b2, b3, mvB);
    K_LOAD(1, a0, a1, a2, a3, mvA);
    __syncthreads();
    for (int kt = 0; kt < 32; kt += 2) {
        {   // even sub-iter: compute tile kt from LDS0; setA holds tile kt+1
            if (kt + 2 < 32) K_LOAD(kt + 2, b0, b1, b2, b3, mvB);
            floatx4 sacc[4];
            COMPUTE_ST(0);
            SOFTMAX_A(0);
            K_WRITE(1, a0, a1, a2, a3, mvA);
            __syncthreads();
        }
        {   // odd sub-iter: compute tile kt+1 from LDS1; setB holds tile kt+2
            if (kt + 3 < 32) K_LOAD(kt + 3, a0, a1, a2, a3, mvA);
            floatx4 sacc[4];
            COMPUTE_ST(1);
            SOFTMAX_A(1);
            if (kt + 2 < 32) K_WRITE(0, b0, b1, b2, b3, mvB);
            __syncthreads();
        }
    }

    // lane merge (once): lgrp 0..3 hold partial (m,l) for q-row (lane&15)
    for (int nt = 0; nt < 4; nt++) {
        float m = m_run[nt], l = l_run[nt];
        for (int off = 16; off <= 32; off <<= 1) {
            float mo = __shfl_xor(m, off);
            float lo2 = __shfl_xor(l, off);
            float mn = fmaxf(m, mo);
            l = l * fexp2(m - mn) + lo2 * fexp2(mo - mn);
            m = mn;
        }
        m_run[nt] = m; l_run[nt] = l;
    }
    // cross-wave merge -> Cn = m_fin + log2(l_total); l_total >= 1 always
    if (lane < 16) {
        for (int nt = 0; nt < 4; nt++) {
            sML[0][wave][nt * 16 + lane] = m_run[nt];
            sML[1][wave][nt * 16 + lane] = l_run[nt];
        }
    }
    __syncthreads();
    float Cn[4];
    for (int nt = 0; nt < 4; nt++) {
        int qr = nt * 16 + lrow;
        float m4 = sML[0][0][qr];
        for (int w = 1; w < 4; w++) m4 = fmaxf(m4, sML[0][w][qr]);
        float ls = 0.f;
        for (int w = 0; w < 4; w++) ls += sML[1][w][qr] * fexp2(sML[0][w][qr] - m4);
        Cn[nt] = m4 + __log2f(ls);    // p = exp2(sm - Cn)
    }

    floatx4 cacc[4];
    for (int j = 0; j < 4; j++) cacc[j] = (floatx4){0.f, 0.f, 0.f, 0.f};

#define PASSB_BODY(KT, CUR) do { \
        int4 vreg[4][2]; \
        for (int j = 0; j < 4; j++) \
            for (int ks = 0; ks < 2; ks++) \
                vreg[j][ks] = *reinterpret_cast<const int4*>( \
                    vt + ((size_t)bh * DH + j * 16 + lrow) * SEQ + (KT) * 64 + ks * 32 + lgrp * 8); \
        floatx4 sacc[4]; \
        COMPUTE_ST(CUR); \
        for (int nt = 0; nt < 4; nt++) { \
            u32 nw = ~sMask[CUR][nt * 16 + lrow][mwsel]; \
            int qr = q0 + nt * 16 + lrow; \
            float4 pf4; \
            float* pp = &pf4.x; \
            for (int r = 0; r < 4; r++) { \
                float sm = ((nw >> (mbit + r)) & 1u) ? sacc[nt][r] : NEGBIG; \
                pp[r] = fexp2(sm - Cn[nt]); \
            } \
            int kc = (KT) * 64 + wave * 16 + lgrp * 4; \
            *reinterpret_cast<float4*>(&attn[((size_t)bh * SEQ + qr) * SEQ + kc]) = pf4; \
            uint2 pw; \
            pw.x = pk_bf16(pp[0], pp[1]); \
            pw.y = pk_bf16(pp[2], pp[3]); \
            *reinterpret_cast<uint2*>(&sP[CUR][KSWZ(nt * 16 + lrow, wave * 16 + lgrp * 4)]) = pw; \
        } \
    } while (0)

#define PASSB_PV(CUR) do { \
        __builtin_amdgcn_s_setprio(1); \
        for (int ks = 0; ks < 2; ks++) { \
            short8v pfrag = *reinterpret_cast<const short8v*>(&sP[CUR][KSWZ(wave * 16 + lrow, ks * 32 + lgrp * 8)]); \
            for (int j = 0; j < 4; j++) { \
                short8v vfrag = *reinterpret_cast<short8v*>(&vreg_pv[j][ks]); \
                cacc[j] = __builtin_amdgcn_mfma_f32_16x16x32_bf16(pfrag, vfrag, cacc[j], 0, 0, 0); \
            } \
        } \
        __builtin_amdgcn_s_setprio(0); \
    } while (0)

    // ---- pass B: prefetch-2 K, dbuf sP, 1 barrier/iter ----
    K_LOAD(0, b0, b1, b2, b3, mvB);
    K_WRITE(0, b0, b1, b2, b3, mvB);
    K_LOAD(1, a0, a1, a2, a3, mvA);
    __syncthreads();
    for (int kt = 0; kt < 32; kt += 2) {
        {   // even sub-iter (tile kt, LDS0)
            if (kt + 2 < 32) K_LOAD(kt + 2, b0, b1, b2, b3, mvB);
            int4 vreg_pv[4][2];
            for (int j = 0; j < 4; j++)
                for (int ks = 0; ks < 2; ks++)
                    vreg_pv[j][ks] = *reinterpret_cast<const int4*>(
                        vt + ((size_t)bh * DH + j * 16 + lrow) * SEQ + kt * 64 + ks * 32 + lgrp * 8);
            floatx4 sacc[4];
            COMPUTE_ST(0);
            for (int nt = 0; nt < 4; nt++) {
                u32 nw = ~sMask[0][nt * 16 + lrow][mwsel];
                int qr = q0 + nt * 16 + lrow;
                float4 pf4;
                float* pp = &pf4.x;
                for (int r = 0; r < 4; r++) {
                    float sm = ((nw >> (mbit + r)) & 1u) ? sacc[nt][r] : NEGBIG;
                    pp[r] = fexp2(sm - Cn[nt]);
                }
                int kc = kt * 64 + wave * 16 + lgrp * 4;
                *reinterpret_cast<float4*>(&attn[((size_t)bh * SEQ + qr) * SEQ + kc]) = pf4;
                uint2 pw;
                pw.x = pk_bf16(pp[0], pp[1]);
                pw.y = pk_bf16(pp[2], pp[3]);
                *reinterpret_cast<uint2*>(&sP[0][KSWZ(nt * 16 + lrow, wave * 16 + lgrp * 4)]) = pw;
            }
            K_WRITE(1, a0, a1, a2, a3, mvA);
            __syncthreads();
            PASSB_PV(0);
        }
        {   // odd sub-iter (tile kt+1, LDS1)
            if (kt + 3 < 32) K_LOAD(kt + 3, a0, a1, a2, a3, mvA);
            int4 vreg_pv[4][2];
            for (int j = 0; j < 4; j++)
                for (int ks = 0; ks < 2; ks++)
                    vreg_pv[j][ks] = *reinterpret_cast<const int4*>(
                        vt + ((size_t)bh * DH + j * 16 + lrow) * SEQ + (kt + 1) * 64 + ks * 32 + lgrp * 8);
            floatx4 sacc[4];
            COMPUTE_ST(1);
            for (int nt = 0; nt < 4; nt++) {
                u32 nw = ~sMask[1][nt * 16 + lrow][mwsel];
                int qr = q0 + nt * 16 + lrow;
                float4 pf4;
                float* pp = &pf4.x;
                for (int r = 0; r < 4; r++) {
                    float sm = ((nw >> (mbit + r)) & 1u) ? sacc[nt][r] : NEGBIG;
                    pp[r] = fexp2(sm - Cn[nt]);
                }
                int kc = (kt + 1) * 64 + wave * 16 + lgrp * 4;
                *reinterpret_cast<float4*>(&attn[((size_t)bh * SEQ + qr) * SEQ + kc]) = pf4;
                uint2 pw;
                pw.x = pk_bf16(pp[0], pp[1]);
                pw.y = pk_bf16(pp[2], pp[3]);
                *reinterpret_cast<uint2*>(&sP[1][KSWZ(nt * 16 + lrow, wave * 16 + lgrp * 4)]) = pw;
            }
            if (kt + 2 < 32) K_WRITE(0, b0, b1, b2, b3, mvB);
            __syncthreads();
            PASSB_PV(1);
        }
    }
    // write context (bf16) into [b, n, h*dh]
    int hh = bh & 15;
    for (int j = 0; j < 4; j++) {
        int d = j * 16 + lrow;
        for (int r = 0; r < 4; r++) {
            int nn = q0 + wave * 16 + lgrp * 4 + r;
            ctx[((size_t)b * SEQ + nn) * DMODEL + hh * 64 + d] = f2bf(cacc[j][r]);
        }
    }
#undef K_LOAD
#undef K_WRITE
#undef COMPUTE_ST
#undef SOFTMAX_A
#undef PASSB_BODY
#undef PASSB_PV
}

// ---------------- out = ctx @ Wfc (natural grid) ----------------
__global__ __launch_bounds__(256, 2) void k_out(
    const u16* __restrict__ ctx, const u16* __restrict__ wfcT, float* __restrict__ out)
{
    __shared__ __attribute__((aligned(16))) u16 sA[128][72];
    __shared__ __attribute__((aligned(16))) u16 sB[128][72];
    int n0 = blockIdx.x * 128;
    int m0 = blockIdx.y * 128;
    int tid = threadIdx.x;
    int wave = tid >> 6, lane = tid & 63;
    int wm = (wave >> 1) * 64, wn = (wave & 1) * 64;
    int lrow = lane & 15, lgrp = lane >> 4;

    floatx4 acc[4][4];
    for (int i = 0; i < 4; i++) for (int j = 0; j < 4; j++) acc[i][j] = (floatx4){0.f, 0.f, 0.f, 0.f};

    int sr = tid >> 1;
    int sc = (tid & 1) * 32;

    for (int k0 = 0; k0 < DMODEL; k0 += 64) {
        const u16* pa = ctx + (size_t)(m0 + sr) * DMODEL + k0 + sc;
        const u16* pb = wfcT + (size_t)(n0 + sr) * DMODEL + k0 + sc;
        for (int i = 0; i < 4; i++) {
            *reinterpret_cast<int4*>(&sA[sr][sc + i * 8]) = *reinterpret_cast<const int4*>(pa + i * 8);
            *reinterpret_cast<int4*>(&sB[sr][sc + i * 8]) = *reinterpret_cast<const int4*>(pb + i * 8);
        }
        __syncthreads();
        for (int ks = 0; ks < 2; ks++) {
            short8v af[4], bf[4];
            for (int i = 0; i < 4; i++) {
                af[i] = *reinterpret_cast<const short8v*>(&sA[wm + i * 16 + lrow][ks * 32 + lgrp * 8]);
                bf[i] = *reinterpret_cast<const short8v*>(&sB[wn + i * 16 + lrow][ks * 32 + lgrp * 8]);
            }
            for (int i = 0; i < 4; i++)
                for (int j = 0; j < 4; j++)
                    acc[i][j] = __builtin_amdgcn_mfma_f32_16x16x32_bf16(af[i], bf[j], acc[i][j], 0, 0, 0);
        }
        __syncthreads();
    }
    for (int i = 0; i < 4; i++)
        for (int j = 0; j < 4; j++)
            for (int r = 0; r < 4; r++) {
                int m = m0 + wm + i * 16 + lgrp * 4 + r;
                int c = n0 + wn + j * 16 + lrow;
                out[(size_t)m * DMODEL + c] = acc[i][j][r];
            }
}

extern "C" void kernel_launch(void* const* d_in, const int* in_sizes, int n_in,
                              void* d_out, int out_size, void* d_ws, size_t ws_size,
                              hipStream_t stream) {
    const float* x    = (const float*)d_in[0];
    const int*   mask = (const int*)d_in[1];
    const float* wqkv = (const float*)d_in[2];
    const float* wfc  = (const float*)d_in[3];

    float* out  = (float*)d_out;
    float* attn = out + (size_t)NBATCH * SEQ * DMODEL;

    u16* xh   = (u16*)d_ws;                 // 4096*1024
    u16* xl   = xh + 4194304;
    u16* whT  = xl + 4194304;               // 3072*1024
    u16* wlT  = whT + 3145728;
    u16* wfcT = wlT + 3145728;              // 1024*1024
    u16* qh   = wfcT + 1048576;             // 32*2048*64 each
    u16* ql   = qh + 4194304;
    u16* kh   = ql + 4194304;
    u16* kl   = kh + 4194304;
    u16* vt   = kl + 4194304;
    u32* mbits = (u32*)(vt + 4194304);      // 2*2048*64 words
    u16* ctx  = xh;                         // overlay: x splits dead after k_qkv

    k_split<<<4096, 256, 0, stream>>>(x, xh, xl, 4194304 / 4);
    k_tsplit<<<dim3(48, 16), 256, 0, stream>>>(wqkv, whT, wlT, 1024, 3072, 1);
    k_tsplit<<<dim3(16, 16), 256, 0, stream>>>(wfc, wfcT, (u16*)nullptr, 1024, 1024, 0);
    k_maskpack<<<32768, 256, 0, stream>>>(mask, (u64*)mbits);
    k_qkv<<<dim3(24, 32), 256, 0, stream>>>(xh, xl, whT, wlT, qh, ql, kh, kl, vt);
    k_attn<<<dim3(32, 32), 256, 4096, stream>>>(qh, ql, kh, kl, vt, mbits, attn, ctx);
    k_out<<<dim3(8, 32), 256, 0, stream>>>(ctx, wfcT, out);
}